// Round 1
// baseline (2426.502 us; speedup 1.0000x reference)
//
#include <hip/hip_runtime.h>
#include <math.h>

// Problem constants (B,C,H,W,K,G fixed by the reference)
#define BB 16
#define CC 64
#define HH 256
#define WW 256
#define HW 65536           // H*W
#define EPS 1e-5f

// ---------------------------------------------------------------------------
// Kernel 1: 3x3 SAME conv, NCHW, C=64->64, + bias  ->  x_conv into workspace
//   tile: 32x32 pixels, CO_PB=16 output channels per block
//   each thread: 2x2 pixel quad x 16 c_out = 64 accumulators
//   LDS: weights [16][64*12] (padded 9->12 for b128 reads) + double-buffered
//        per-c_in input tile 34x34 (pitch 35)
// ---------------------------------------------------------------------------
#define TS 32
#define CO_PB 16
#define XPITCH 35

__global__ __launch_bounds__(256, 2)
void conv3x3_kernel(const float* __restrict__ x,
                    const float* __restrict__ w,
                    const float* __restrict__ bias,
                    float* __restrict__ xc)
{
    __shared__ float ws[CO_PB][64 * 12];
    __shared__ float xs[2][34 * XPITCH];

    const int tid = threadIdx.x;
    // swizzled grid: x = (tile_x<<2)|cog so the 4 cog blocks of a tile are
    // adjacent in dispatch order (L2 reuse of the same x tile)
    const int cog = blockIdx.x & 3;
    const int tx  = (blockIdx.x >> 2) * TS;
    const int ty  = blockIdx.y * TS;
    const int b   = blockIdx.z;
    const int co0 = cog * CO_PB;

    // stage weights: ws[co][ci*12+k] = w[(co0+co)*576 + ci*9 + k]
    for (int i = tid; i < CO_PB * 576; i += 256) {
        int co = i / 576;
        int r  = i - co * 576;
        int ci = r / 9;
        int k  = r - ci * 9;
        ws[co][ci * 12 + k] = w[(co0 + co) * 576 + r];
    }

    const int qx  = tid & 15;       // quad col  (pixel base 2*qx)
    const int qy  = tid >> 4;       // quad row  (pixel base 2*qy)
    const int px0 = 2 * qx;
    const int py0 = 2 * qy;

    float acc[2][2][CO_PB];
#pragma unroll
    for (int py = 0; py < 2; ++py)
#pragma unroll
        for (int px = 0; px < 2; ++px)
#pragma unroll
            for (int co = 0; co < CO_PB; ++co)
                acc[py][px][co] = 0.f;

    const float* xb = x + (size_t)b * CC * HW;

    // stage one input-channel tile (34x34 with zero halo) into dst
    auto stage = [&](int ci, float* dst) {
        const float* xp = xb + (size_t)ci * HW;
#pragma unroll
        for (int it = 0; it < 5; ++it) {
            int i = tid + it * 256;
            if (i < 34 * 34) {
                int r  = i / 34;
                int c  = i - r * 34;
                int gy = ty + r - 1;
                int gx = tx + c - 1;
                float v = 0.f;
                if ((unsigned)gy < (unsigned)HH && (unsigned)gx < (unsigned)WW)
                    v = xp[gy * WW + gx];
                dst[r * XPITCH + c] = v;
            }
        }
    };

    stage(0, xs[0]);
    __syncthreads();

    for (int ci = 0; ci < CC; ++ci) {
        const float* xsb = xs[ci & 1];
        if (ci < CC - 1)
            stage(ci + 1, xs[(ci & 1) ^ 1]);

        // 4x4 input patch for the 2x2 quad
        float xv[4][4];
#pragma unroll
        for (int dy = 0; dy < 4; ++dy)
#pragma unroll
            for (int dx = 0; dx < 4; ++dx)
                xv[dy][dx] = xsb[(py0 + dy) * XPITCH + px0 + dx];

#pragma unroll
        for (int co = 0; co < CO_PB; ++co) {
            const float* wp = &ws[co][ci * 12];
            float wv[9];
#pragma unroll
            for (int k = 0; k < 9; ++k) wv[k] = wp[k];
#pragma unroll
            for (int py = 0; py < 2; ++py)
#pragma unroll
                for (int px = 0; px < 2; ++px) {
                    float s = acc[py][px][co];
#pragma unroll
                    for (int ky = 0; ky < 3; ++ky)
#pragma unroll
                        for (int kx = 0; kx < 3; ++kx)
                            s = fmaf(wv[ky * 3 + kx], xv[py + ky][px + kx], s);
                    acc[py][px][co] = s;
                }
        }
        __syncthreads();
    }

    // epilogue: + bias, write x_conv
#pragma unroll
    for (int co = 0; co < CO_PB; ++co) {
        float bv = bias[co0 + co];
        float* op = xc + ((size_t)b * CC + co0 + co) * HW;
#pragma unroll
        for (int py = 0; py < 2; ++py)
#pragma unroll
            for (int px = 0; px < 2; ++px)
                op[(ty + py0 + py) * WW + tx + px0 + px] =
                    acc[py][px][co] + bv;
    }
}

// ---------------------------------------------------------------------------
// Kernel 2: fused epilogue.
//   Per 16x16 pixel tile: stage x_conv (with 1-px halo) in two 32-channel
//   chunks. Per pixel: group mean/var over channels (center px only),
//   depthwise diag-conv + bias, groupnorm affine, tanh * hardswish-gate,
//   residual add, online logsumexp over channels -> out[B,1,H,W].
// ---------------------------------------------------------------------------
__global__ __launch_bounds__(256, 2)
void epilogue_kernel(const float* __restrict__ xc,
                     const float* __restrict__ w,
                     const float* __restrict__ bias,
                     const float* __restrict__ gscale,
                     const float* __restrict__ gbias,
                     float* __restrict__ out)
{
    __shared__ float xcs[32][18 * 18];   // 32-channel chunk, 18x18 halo tile
    __shared__ float wd[64][9];          // diag weights w[c,c,:,:]
    __shared__ float cb[64], gsc[64], gbi[64];

    const int tid = threadIdx.x;
    const int tx  = blockIdx.x * 16;
    const int ty  = blockIdx.y * 16;
    const int b   = blockIdx.z;

    if (tid < 64) {
        cb[tid]  = bias[tid];
        gsc[tid] = gscale[tid];
        gbi[tid] = gbias[tid];
    }
    for (int i = tid; i < 576; i += 256) {
        int c = i / 9, k = i - c * 9;
        wd[c][k] = w[c * 585 + k];       // w[c*576 + c*9 + k]
    }

    const int lx = tid & 15;
    const int ly = tid >> 4;
    const float* xcb = xc + (size_t)b * CC * HW;

    float m = -INFINITY, ssum = 0.f;

    for (int half = 0; half < 2; ++half) {
        __syncthreads();   // previous chunk fully consumed (also covers wd/cb)
        // stage 32 channels x 18x18
#pragma unroll 4
        for (int it = 0; it < 41; ++it) {
            int i = tid + it * 256;
            if (i < 32 * 324) {
                int c   = i / 324;
                int r2  = i - c * 324;
                int r   = r2 / 18;
                int col = r2 - r * 18;
                int gy = ty + r - 1;
                int gx = tx + col - 1;
                float v = 0.f;
                if ((unsigned)gy < (unsigned)HH && (unsigned)gx < (unsigned)WW)
                    v = xcb[((size_t)(half * 32 + c)) * HW + gy * WW + gx];
                xcs[c][r * 18 + col] = v;
            }
        }
        __syncthreads();

        // group stats (4 groups of 8 channels in this chunk), center pixel
        float mean[4], inv[4];
#pragma unroll
        for (int g = 0; g < 4; ++g) {
            float s = 0.f, s2 = 0.f;
#pragma unroll
            for (int j = 0; j < 8; ++j) {
                float v = xcs[g * 8 + j][(ly + 1) * 18 + lx + 1];
                s += v; s2 = fmaf(v, v, s2);
            }
            float mn = s * 0.125f;
            float vr = fmaxf(s2 * 0.125f - mn * mn, 0.f);
            mean[g] = mn;
            inv[g]  = rsqrtf(vr + EPS);
        }

        for (int cl = 0; cl < 32; ++cl) {
            int c = half * 32 + cl;
            int g = cl >> 3;
            const float* xp = &xcs[cl][ly * 18 + lx];   // 3x3 top-left
            const float* wp = wd[c];
            float a = cb[c];
            a = fmaf(wp[0], xp[0],  a);
            a = fmaf(wp[1], xp[1],  a);
            a = fmaf(wp[2], xp[2],  a);
            a = fmaf(wp[3], xp[18], a);
            a = fmaf(wp[4], xp[19], a);
            a = fmaf(wp[5], xp[20], a);
            a = fmaf(wp[6], xp[36], a);
            a = fmaf(wp[7], xp[37], a);
            a = fmaf(wp[8], xp[38], a);
            float xcv  = xp[19];                         // center x_conv
            float nrm  = (a - mean[g]) * inv[g] * gsc[c] + gbi[c];
            float gate = fminf(fmaxf((nrm + 3.f) * (1.f / 6.f), 0.f), 1.f);
            float fus  = tanhf(nrm) * gate;
            float v    = xcv + fus;
            // online logsumexp
            float nm = fmaxf(m, v);
            ssum = fmaf(ssum, __expf(m - nm), __expf(v - nm));
            m = nm;
        }
    }

    out[(size_t)b * HW + (ty + ly) * WW + tx + lx] = m + logf(ssum);
}

// ---------------------------------------------------------------------------
extern "C" void kernel_launch(void* const* d_in, const int* in_sizes, int n_in,
                              void* d_out, int out_size, void* d_ws, size_t ws_size,
                              hipStream_t stream)
{
    (void)in_sizes; (void)n_in; (void)out_size; (void)ws_size;
    const float* x   = (const float*)d_in[0];
    const float* w   = (const float*)d_in[1];
    const float* cb  = (const float*)d_in[2];
    const float* gsc = (const float*)d_in[3];
    const float* gbi = (const float*)d_in[4];
    float* out   = (float*)d_out;
    float* xconv = (float*)d_ws;    // needs B*C*H*W*4 = 256 MiB of workspace

    dim3 g1(4 * (WW / TS), HH / TS, BB);   // (32, 8, 16)
    conv3x3_kernel<<<g1, dim3(256), 0, stream>>>(x, w, cb, xconv);

    dim3 g2(WW / 16, HH / 16, BB);         // (16, 16, 16)
    epilogue_kernel<<<g2, dim3(256), 0, stream>>>(xconv, w, cb, gsc, gbi, out);
}

// Round 2
// 666.163 us; speedup vs baseline: 3.6425x; 3.6425x over previous
//
#include <hip/hip_runtime.h>
#include <math.h>

// Problem constants
#define BB 16
#define CC 64
#define HH 256
#define WW 256
#define HW 65536
#define EPS 1e-5f

typedef __attribute__((ext_vector_type(8))) short short8;
typedef __attribute__((ext_vector_type(16))) float f32x16;

__device__ __forceinline__ float bf2f(unsigned short u) {
    union { unsigned int i; float f; } c; c.i = ((unsigned int)u) << 16; return c.f;
}
__device__ __forceinline__ unsigned short f2bf(float f) {
    union { float f; unsigned int i; } c; c.f = f;
    unsigned int r = (c.i + 0x7FFFu + ((c.i >> 16) & 1u)) >> 16;
    return (unsigned short)r;
}

// ---------------------------------------------------------------------------
// Kernel 0: weights fp32 -> bf16 fragment layout
//   wf[t][kg][co][j]  (t=tap 0..8, kg=ci>>3 0..7, co 0..63, j=ci&7)
//   flat: t*4096 + kg*512 + co*8 + j     (granule = kg*64+co, 16B each)
// ---------------------------------------------------------------------------
__global__ void wprep_kernel(const float* __restrict__ w, unsigned short* __restrict__ wf)
{
    for (int i = threadIdx.x; i < 64 * 576; i += 256) {
        int co = i / 576;
        int r  = i - co * 576;
        int ci = r / 9;
        int t  = r - ci * 9;
        int kg = ci >> 3;
        int j  = ci & 7;
        wf[t * 4096 + kg * 512 + co * 8 + j] = f2bf(w[i]);
    }
}

// ---------------------------------------------------------------------------
// Kernel 1: x NCHW fp32 -> xt NHWC bf16.  Tile: 32 px x 64 ci per block.
// ---------------------------------------------------------------------------
__global__ __launch_bounds__(256) void transpose_kernel(const float* __restrict__ x,
                                                        unsigned short* __restrict__ xt)
{
    __shared__ float t[64 * 36];          // [ci][pitch 36], quad-rotated
    const int tid = threadIdx.x;
    const int x0  = blockIdx.x * 32;
    const int y   = blockIdx.y;
    const int b   = blockIdx.z;

    // phase 1: coalesced fp32 reads, rotated LDS writes (float4)
#pragma unroll
    for (int it = 0; it < 2; ++it) {
        int flat = it * 1024 + tid * 4;
        int px = flat & 31;
        int ci = flat >> 5;
        const float4 v = *(const float4*)(x + ((size_t)(b * 64 + ci) * HW + y * WW + x0 + px));
        int pxr = (px + 4 * (ci >> 3)) & 31;
        *(float4*)(t + ci * 36 + pxr) = v;
    }
    __syncthreads();

    // phase 2: gather 8 ci for one pixel, pack bf16, b128 store (fully coalesced)
    int px = tid >> 3;
    int kg = tid & 7;
    short8 o;
#pragma unroll
    for (int j = 0; j < 8; ++j) {
        int ci = kg * 8 + j;
        float v = t[ci * 36 + ((px + 4 * (ci >> 3)) & 31)];
        o[j] = (short)f2bf(v);
    }
    *(short8*)(xt + ((size_t)(b * HW + y * WW + x0 + px) * 64 + kg * 8)) = o;
}

// ---------------------------------------------------------------------------
// Kernel 2: implicit-GEMM conv via MFMA 32x32x16 bf16.
//   Block: 32x8 pixel tile x 64 c_out. Per tap (ky,kx): D[pix][co] += X*Wk.
//   A-frag = x tile rows (m=pixel), B-frag = weights (n=co). D cols = co ->
//   stores are NHWC-contiguous.
//   LDS: xlds 34x10 halo x 64ci bf16 (43.5 KB, XOR-swizzled granules),
//        wbuf double-buffered per-tap weights (2 x 8 KB). Total 59.9 KB.
// ---------------------------------------------------------------------------
__global__ __launch_bounds__(256, 2)
void conv_mfma_kernel(const unsigned short* __restrict__ xt,
                      const unsigned short* __restrict__ wf,
                      const float* __restrict__ bias,
                      unsigned short* __restrict__ xc)
{
    __shared__ unsigned short xlds[340 * 64];      // 43,520 B
    __shared__ unsigned short wbuf[2][4096];       // 2 x 8,192 B

    const int tid = threadIdx.x;
    const int tx  = blockIdx.x * 32;
    const int ty  = blockIdx.y * 8;
    const int b   = blockIdx.z;
    const size_t bHW = (size_t)b * HW;

    // ---- stage x tile (34x10 halo, 2720 granules of 16B), swizzled ----
#pragma unroll
    for (int it = 0; it < 11; ++it) {
        int g = tid + it * 256;
        if (g < 2720) {
            int pix = g >> 3;
            int kg  = g & 7;
            int hy  = (unsigned)pix / 34u;
            int hx  = pix - hy * 34;
            int gy  = ty + hy - 1;
            int gx  = tx + hx - 1;
            short8 v = {};
            if ((unsigned)gy < (unsigned)HH && (unsigned)gx < (unsigned)WW)
                v = *(const short8*)(xt + ((bHW + gy * WW + gx) * 64 + kg * 8));
            *(short8*)(xlds + (pix * 8 + (kg ^ (pix & 7))) * 8) = v;
        }
    }
    // ---- stage tap-0 weights ----
#pragma unroll
    for (int it = 0; it < 2; ++it) {
        int g = tid + it * 256;
        *(short8*)(&wbuf[0][g * 8]) = *(const short8*)(wf + g * 8);
    }
    __syncthreads();

    const int lane = tid & 63;
    const int wv   = tid >> 6;
    const int m    = lane & 31;     // pixel-in-row for A, co-in-tile for B
    const int half = lane >> 5;
    const int pr0  = 2 * wv;
    const int pr1  = 2 * wv + 1;

    f32x16 acc00, acc01, acc10, acc11;
#pragma unroll
    for (int i = 0; i < 16; ++i) { acc00[i] = 0.f; acc01[i] = 0.f; acc10[i] = 0.f; acc11[i] = 0.f; }

#pragma unroll
    for (int t = 0; t < 9; ++t) {
        const int ky = t / 3, kx = t - 3 * (t / 3);
        // prefetch next tap's weights into other buffer
        if (t < 8) {
#pragma unroll
            for (int it = 0; it < 2; ++it) {
                int g = tid + it * 256;
                *(short8*)(&wbuf[(t + 1) & 1][g * 8]) =
                    *(const short8*)(wf + (t + 1) * 4096 + g * 8);
            }
        }
        const unsigned short* wb = wbuf[t & 1];
        const int pl0 = (pr0 + ky) * 34 + m + kx;
        const int pl1 = (pr1 + ky) * 34 + m + kx;
#pragma unroll
        for (int ks = 0; ks < 4; ++ks) {
            const int kg = ks * 2 + half;
            short8 a0 = *(const short8*)(xlds + (pl0 * 8 + (kg ^ (pl0 & 7))) * 8);
            short8 a1 = *(const short8*)(xlds + (pl1 * 8 + (kg ^ (pl1 & 7))) * 8);
            short8 b0 = *(const short8*)(wb + (kg * 64 + m) * 8);
            short8 b1 = *(const short8*)(wb + (kg * 64 + 32 + m) * 8);
            acc00 = __builtin_amdgcn_mfma_f32_32x32x16_bf16(a0, b0, acc00, 0, 0, 0);
            acc01 = __builtin_amdgcn_mfma_f32_32x32x16_bf16(a0, b1, acc01, 0, 0, 0);
            acc10 = __builtin_amdgcn_mfma_f32_32x32x16_bf16(a1, b0, acc10, 0, 0, 0);
            acc11 = __builtin_amdgcn_mfma_f32_32x32x16_bf16(a1, b1, acc11, 0, 0, 0);
        }
        __syncthreads();
    }

    // ---- store: D[row=pixel][col=co], col = lane&31 -> NHWC contiguous ----
    const float bv0 = bias[m];
    const float bv1 = bias[32 + m];
#pragma unroll
    for (int reg = 0; reg < 16; ++reg) {
        int px = (reg & 3) + 8 * (reg >> 2) + 4 * half;
        size_t base0 = (bHW + (ty + pr0) * WW + tx + px) * 64;
        size_t base1 = (bHW + (ty + pr1) * WW + tx + px) * 64;
        xc[base0 + m]      = f2bf(acc00[reg] + bv0);
        xc[base0 + 32 + m] = f2bf(acc01[reg] + bv1);
        xc[base1 + m]      = f2bf(acc10[reg] + bv0);
        xc[base1 + 32 + m] = f2bf(acc11[reg] + bv1);
    }
}

// ---------------------------------------------------------------------------
// Kernel 3: fused epilogue on NHWC bf16 x_conv.
//   Block: 16x16 pixels; stage 18x18 halo x 64ch (41.5 KB, swizzled).
//   Per thread (one pixel): per 8-ch granule (== one GN group): depthwise
//   diag conv, group stats, affine, tanh*hardswish gate, residual, online LSE.
// ---------------------------------------------------------------------------
__global__ __launch_bounds__(256, 3)
void epilogue_kernel(const unsigned short* __restrict__ xc,
                     const float* __restrict__ w,
                     const float* __restrict__ cb,
                     const float* __restrict__ gs,
                     const float* __restrict__ gb,
                     float* __restrict__ out)
{
    __shared__ unsigned short xs[324 * 64];        // 41,472 B

    const int tid = threadIdx.x;
    const int tx  = blockIdx.x * 16;
    const int ty  = blockIdx.y * 16;
    const int b   = blockIdx.z;
    const size_t bHW = (size_t)b * HW;

#pragma unroll
    for (int it = 0; it < 11; ++it) {
        int g = tid + it * 256;
        if (g < 2592) {
            int pix = g >> 3;
            int kg  = g & 7;
            int hy  = (unsigned)pix / 18u;
            int hx  = pix - hy * 18;
            int gy  = ty + hy - 1;
            int gx  = tx + hx - 1;
            short8 v = {};
            if ((unsigned)gy < (unsigned)HH && (unsigned)gx < (unsigned)WW)
                v = *(const short8*)(xc + ((bHW + gy * WW + gx) * 64 + kg * 8));
            *(short8*)(xs + (pix * 8 + (kg ^ (pix & 7))) * 8) = v;
        }
    }
    __syncthreads();

    const int lx = tid & 15;
    const int ly = tid >> 4;

    float mmax = -INFINITY, ssum = 0.f;

#pragma unroll 2
    for (int kg = 0; kg < 8; ++kg) {
        // 9 neighbor granules (8 channels each)
        short8 n[9];
#pragma unroll
        for (int dy = 0; dy < 3; ++dy)
#pragma unroll
            for (int dx = 0; dx < 3; ++dx) {
                int pl = (ly + dy) * 18 + (lx + dx);
                n[dy * 3 + dx] = *(const short8*)(xs + (pl * 8 + (kg ^ (pl & 7))) * 8);
            }
        // group stats over the 8 center-pixel channels (group == granule)
        float xcv[8];
        float s = 0.f, s2 = 0.f;
#pragma unroll
        for (int c = 0; c < 8; ++c) {
            xcv[c] = bf2f((unsigned short)n[4][c]);
            s += xcv[c];
            s2 = fmaf(xcv[c], xcv[c], s2);
        }
        float mean = s * 0.125f;
        float var  = fmaxf(s2 * 0.125f - mean * mean, 0.f);
        float inv  = rsqrtf(var + EPS);

#pragma unroll
        for (int c = 0; c < 8; ++c) {
            int ch = kg * 8 + c;
            float a = cb[ch];
#pragma unroll
            for (int k = 0; k < 9; ++k)
                a = fmaf(w[ch * 585 + k], bf2f((unsigned short)n[k][c]), a);
            float nrm  = (a - mean) * inv * gs[ch] + gb[ch];
            float gate = fminf(fmaxf((nrm + 3.f) * (1.f / 6.f), 0.f), 1.f);
            float e    = __expf(2.f * nrm);
            float th   = 1.f - 2.f / (e + 1.f);
            float v    = xcv[c] + th * gate;
            float nm   = fmaxf(mmax, v);
            ssum = fmaf(ssum, __expf(mmax - nm), __expf(v - nm));
            mmax = nm;
        }
    }

    out[bHW + (ty + ly) * WW + tx + lx] = mmax + __logf(ssum);
}

// ---------------------------------------------------------------------------
extern "C" void kernel_launch(void* const* d_in, const int* in_sizes, int n_in,
                              void* d_out, int out_size, void* d_ws, size_t ws_size,
                              hipStream_t stream)
{
    (void)in_sizes; (void)n_in; (void)out_size;
    const float* x   = (const float*)d_in[0];
    const float* w   = (const float*)d_in[1];
    const float* cbp = (const float*)d_in[2];
    const float* gsp = (const float*)d_in[3];
    const float* gbp = (const float*)d_in[4];
    float* out = (float*)d_out;

    const size_t XB = (size_t)134217728;   // one NHWC bf16 tensor
    unsigned short* xt  = (unsigned short*)d_ws;
    unsigned short* xcb = (unsigned short*)((char*)d_ws + XB);
    // bf16 fragment weights (73,728 B): tail of ws if it fits, else stash in
    // d_out's 4 MB (epilogue fully overwrites d_out afterwards).
    unsigned short* wf = (ws_size >= 2 * XB + 73728)
                             ? (unsigned short*)((char*)d_ws + 2 * XB)
                             : (unsigned short*)d_out;

    wprep_kernel<<<dim3(1), dim3(256), 0, stream>>>(w, wf);
    transpose_kernel<<<dim3(8, 256, 16), dim3(256), 0, stream>>>(x, xt);
    conv_mfma_kernel<<<dim3(8, 32, 16), dim3(256), 0, stream>>>(xt, wf, cbp, xcb);
    epilogue_kernel<<<dim3(16, 16, 16), dim3(256), 0, stream>>>(xcb, w, cbp, gsp, gbp, out);
}

// Round 3
// 650.259 us; speedup vs baseline: 3.7316x; 1.0245x over previous
//
#include <hip/hip_runtime.h>
#include <math.h>

// Problem constants
#define HH 256
#define WW 256
#define HW 65536
#define EPS 1e-5f

typedef __attribute__((ext_vector_type(8))) short short8;
typedef __attribute__((ext_vector_type(16))) float f32x16;

__device__ __forceinline__ float bf2f(unsigned short u) {
    union { unsigned int i; float f; } c; c.i = ((unsigned int)u) << 16; return c.f;
}
__device__ __forceinline__ unsigned short f2bf(float f) {
    union { float f; unsigned int i; } c; c.f = f;
    return (unsigned short)((c.i + 0x7FFFu + ((c.i >> 16) & 1u)) >> 16);
}

// ---------------------------------------------------------------------------
// Kernel 0: weights fp32 -> bf16 B-fragment layout, one tap per block.
//   wf[t][kg][co][j]: flat t*4096 + kg*512 + co*8 + j  (ci = kg*8+j)
// ---------------------------------------------------------------------------
__global__ void wprep_kernel(const float* __restrict__ w, unsigned short* __restrict__ wf)
{
    const int t = blockIdx.x;                 // tap 0..8
    for (int i = threadIdx.x; i < 4096; i += 256) {
        int kg = i >> 9;
        int r  = i & 511;
        int co = r >> 3;
        int j  = r & 7;
        int ci = kg * 8 + j;
        wf[t * 4096 + i] = f2bf(w[co * 576 + ci * 9 + t]);
    }
}

// ---------------------------------------------------------------------------
// Kernel 1: x NCHW fp32 -> xt NHWC bf16.  Tile: 32 px x 64 ci per block.
// ---------------------------------------------------------------------------
__global__ __launch_bounds__(256) void transpose_kernel(const float* __restrict__ x,
                                                        unsigned short* __restrict__ xt)
{
    __shared__ float t[64 * 36];          // [ci][pitch 36], quad-rotated
    const int tid = threadIdx.x;
    const int x0  = blockIdx.x * 32;
    const int y   = blockIdx.y;
    const int b   = blockIdx.z;

#pragma unroll
    for (int it = 0; it < 2; ++it) {
        int flat = it * 1024 + tid * 4;
        int px = flat & 31;
        int ci = flat >> 5;
        const float4 v = *(const float4*)(x + ((size_t)(b * 64 + ci) * HW + y * WW + x0 + px));
        int pxr = (px + 4 * (ci >> 3)) & 31;
        *(float4*)(t + ci * 36 + pxr) = v;
    }
    __syncthreads();

    int px = tid >> 3;
    int kg = tid & 7;
    short8 o;
#pragma unroll
    for (int j = 0; j < 8; ++j) {
        int ci = kg * 8 + j;
        float v = t[ci * 36 + ((px + 4 * (ci >> 3)) & 31)];
        o[j] = (short)f2bf(v);
    }
    *(short8*)(xt + ((size_t)(b * HW + y * WW + x0 + px) * 64 + kg * 8)) = o;
}

// ---------------------------------------------------------------------------
// Kernel 2: FUSED conv(3x3, MFMA implicit GEMM) + full epilogue.
//   Out tile 32x8 per block. x_conv recomputed on 34x10 halo tile:
//   340 px -> 11 M-tiles of 32 (waves take 3/3/3/2), N = 64 co = 2 tiles.
//   x staged 36x12 halo, bf16 NHWC granules, XOR-swizzled (55.3 KB).
//   After taps, x_conv(+bias, zeroed outside image) is written back into the
//   SAME LDS buffer; epilogue (group stats over channels, depthwise diag
//   conv, affine, tanh*hardswish, residual, channel-LSE) runs in-block.
//   LDS: xs 55296 B + wbuf 16384 B = 71.7 KB -> 2 blocks/CU.
// ---------------------------------------------------------------------------
__global__ __launch_bounds__(256, 2)
void conv_fused_kernel(const unsigned short* __restrict__ xt,
                       const unsigned short* __restrict__ wf,
                       const float* __restrict__ bias,
                       const float* __restrict__ w,
                       const float* __restrict__ gs,
                       const float* __restrict__ gb,
                       float* __restrict__ out)
{
    __shared__ unsigned short xs[432 * 64];        // x tile; reused for x_conv (340*64)
    __shared__ unsigned short wbuf[2][4096];       // per-tap weights; reused for params

    const int tid = threadIdx.x;
    const int tx  = blockIdx.x * 32;
    const int ty  = blockIdx.y * 8;
    const int b   = blockIdx.z;
    const size_t bHW = (size_t)b * HW;

    // ---- stage x tile 36x12 (origin tx-2, ty-2), swizzled granules ----
#pragma unroll
    for (int it = 0; it < 14; ++it) {
        int g = tid + it * 256;
        if (g < 3456) {
            int pix = g >> 3;
            int kg  = g & 7;
            int hy  = (int)((unsigned)pix / 36u);
            int hx  = pix - hy * 36;
            int gy  = ty + hy - 2;
            int gx  = tx + hx - 2;
            short8 v = {};
            if ((unsigned)gy < (unsigned)HH && (unsigned)gx < (unsigned)WW)
                v = *(const short8*)(xt + ((bHW + gy * WW + gx) * 64 + kg * 8));
            *(short8*)(xs + (pix * 8 + (kg ^ (pix & 7))) * 8) = v;
        }
    }
#pragma unroll
    for (int it = 0; it < 2; ++it) {
        int g = tid + it * 256;
        *(short8*)(&wbuf[0][g * 8]) = *(const short8*)(wf + g * 8);
    }
    __syncthreads();

    const int lane = tid & 63;
    const int wv   = tid >> 6;
    const int m    = lane & 31;
    const int half = lane >> 5;
    const int nt   = (wv < 3) ? 3 : 2;   // M-tiles this wave owns
    const int t0   = wv * 3;

    // per-lane base pixel index in the 36-wide staging grid, per M-tile
    int pb[3];
#pragma unroll
    for (int i = 0; i < 3; ++i) {
        int p = (t0 + i) * 32 + m;
        if (p > 339) p = 339;            // clamp (results discarded at store)
        int py = (int)((unsigned)p / 34u);
        pb[i] = py * 36 + (p - py * 34);
    }

    f32x16 acc[3][2];
#pragma unroll
    for (int i = 0; i < 3; ++i)
#pragma unroll
        for (int n = 0; n < 2; ++n)
#pragma unroll
            for (int r = 0; r < 16; ++r) acc[i][n][r] = 0.f;

#pragma unroll
    for (int t9 = 0; t9 < 9; ++t9) {
        const int ky  = t9 / 3;
        const int kx  = t9 - 3 * ky;
        const int off = ky * 36 + kx;
        if (t9 < 8) {                     // prefetch next tap's weights
#pragma unroll
            for (int it = 0; it < 2; ++it) {
                int g = tid + it * 256;
                *(short8*)(&wbuf[(t9 + 1) & 1][g * 8]) =
                    *(const short8*)(wf + (t9 + 1) * 4096 + g * 8);
            }
        }
        const unsigned short* wb = wbuf[t9 & 1];
#pragma unroll
        for (int ks = 0; ks < 4; ++ks) {
            const int kg = ks * 2 + half;
            short8 bf0 = *(const short8*)(wb + (kg * 64 + m) * 8);
            short8 bf1 = *(const short8*)(wb + (kg * 64 + 32 + m) * 8);
#pragma unroll
            for (int i = 0; i < 3; ++i) {
                if (i < nt) {
                    int pi = pb[i] + off;
                    short8 a = *(const short8*)(xs + (pi * 8 + (kg ^ (pi & 7))) * 8);
                    acc[i][0] = __builtin_amdgcn_mfma_f32_32x32x16_bf16(a, bf0, acc[i][0], 0, 0, 0);
                    acc[i][1] = __builtin_amdgcn_mfma_f32_32x32x16_bf16(a, bf1, acc[i][1], 0, 0, 0);
                }
            }
        }
        __syncthreads();
    }

    // ---- write x_conv (+bias; zero outside image) into xs (34x10 grid) ----
    const float bv0 = bias[m];
    const float bv1 = bias[32 + m];
    const int kg0 = m >> 3;
    const int kg1 = 4 + (m >> 3);
#pragma unroll
    for (int i = 0; i < 3; ++i) {
        if (i < nt) {
#pragma unroll
            for (int reg = 0; reg < 16; ++reg) {
                int row = (reg & 3) + 8 * (reg >> 2) + 4 * half;
                int p   = (t0 + i) * 32 + row;
                if (p < 340) {
                    int py = (int)((unsigned)p / 34u);
                    int px = p - py * 34;
                    int gy = ty + py - 1;
                    int gx = tx + px - 1;
                    bool inr = (unsigned)gy < (unsigned)HH && (unsigned)gx < (unsigned)WW;
                    unsigned short v0 = inr ? f2bf(acc[i][0][reg] + bv0) : (unsigned short)0;
                    unsigned short v1 = inr ? f2bf(acc[i][1][reg] + bv1) : (unsigned short)0;
                    xs[(p * 8 + (kg0 ^ (p & 7))) * 8 + (m & 7)] = v0;
                    xs[(p * 8 + (kg1 ^ (p & 7))) * 8 + (m & 7)] = v1;
                }
            }
        }
    }
    // ---- stage epilogue params into wbuf region (last wbuf read was tap 8) ----
    float* prm = (float*)wbuf;           // wd[576] | cb[64] | gsc[64] | gbi[64]
    for (int i = tid; i < 576; i += 256) {
        int c = (int)((unsigned)i / 9u);
        int k = i - c * 9;
        prm[i] = w[c * 585 + k];         // diag weight w[c,c,ky,kx]
    }
    if (tid < 64) {
        prm[576 + tid] = bias[tid];
        prm[640 + tid] = gs[tid];
        prm[704 + tid] = gb[tid];
    }
    __syncthreads();

    // ---- epilogue: one thread per output pixel (32x8) ----
    const int lx = tid & 31;
    const int ly = tid >> 5;
    const float* wd  = prm;
    const float* cbp = prm + 576;
    const float* gsp = prm + 640;
    const float* gbp = prm + 704;

    float mmax = -INFINITY, ssum = 0.f;

#pragma unroll 2
    for (int kg = 0; kg < 8; ++kg) {     // granule == groupnorm group (8 ch)
        short8 n9[9];
#pragma unroll
        for (int dy = 0; dy < 3; ++dy)
#pragma unroll
            for (int dx = 0; dx < 3; ++dx) {
                int pl = (ly + dy) * 34 + (lx + dx);
                n9[dy * 3 + dx] = *(const short8*)(xs + (pl * 8 + (kg ^ (pl & 7))) * 8);
            }
        float xcv[8], s = 0.f, s2 = 0.f;
#pragma unroll
        for (int c = 0; c < 8; ++c) {
            xcv[c] = bf2f((unsigned short)n9[4][c]);
            s += xcv[c];
            s2 = fmaf(xcv[c], xcv[c], s2);
        }
        float mean = s * 0.125f;
        float var  = fmaxf(s2 * 0.125f - mean * mean, 0.f);
        float inv  = rsqrtf(var + EPS);

#pragma unroll
        for (int c = 0; c < 8; ++c) {
            int ch = kg * 8 + c;
            float a = cbp[ch];
#pragma unroll
            for (int k = 0; k < 9; ++k)
                a = fmaf(wd[ch * 9 + k], bf2f((unsigned short)n9[k][c]), a);
            float nrm  = (a - mean) * inv * gsp[ch] + gbp[ch];
            float gate = fminf(fmaxf((nrm + 3.f) * (1.f / 6.f), 0.f), 1.f);
            float e    = __expf(2.f * nrm);
            float th   = 1.f - 2.f / (e + 1.f);
            float v    = xcv[c] + th * gate;
            float nm   = fmaxf(mmax, v);
            ssum = fmaf(ssum, __expf(mmax - nm), __expf(v - nm));
            mmax = nm;
        }
    }

    out[bHW + (ty + ly) * WW + tx + lx] = mmax + __logf(ssum);
}

// ---------------------------------------------------------------------------
extern "C" void kernel_launch(void* const* d_in, const int* in_sizes, int n_in,
                              void* d_out, int out_size, void* d_ws, size_t ws_size,
                              hipStream_t stream)
{
    (void)in_sizes; (void)n_in; (void)out_size;
    const float* x   = (const float*)d_in[0];
    const float* w   = (const float*)d_in[1];
    const float* cbp = (const float*)d_in[2];
    const float* gsp = (const float*)d_in[3];
    const float* gbp = (const float*)d_in[4];
    float* out = (float*)d_out;

    const size_t XB = (size_t)134217728;   // NHWC bf16 x tensor (128 MiB)
    unsigned short* xtp = (unsigned short*)d_ws;
    // wf (72 KiB) after xt; d_out fallback only if ws is tiny (not expected).
    unsigned short* wfp = (ws_size >= XB + 73728)
                              ? (unsigned short*)((char*)d_ws + XB)
                              : (unsigned short*)d_out;

    wprep_kernel<<<dim3(9), dim3(256), 0, stream>>>(w, wfp);
    transpose_kernel<<<dim3(8, 256, 16), dim3(256), 0, stream>>>(x, xtp);
    conv_fused_kernel<<<dim3(8, 32, 16), dim3(256), 0, stream>>>(xtp, wfp, cbp, w, gsp, gbp, out);
}

// Round 4
// 633.177 us; speedup vs baseline: 3.8323x; 1.0270x over previous
//
#include <hip/hip_runtime.h>
#include <math.h>

// Problem constants
#define HH 256
#define WW 256
#define HW 65536
#define EPS 1e-5f

typedef __attribute__((ext_vector_type(8))) short short8;
typedef __attribute__((ext_vector_type(16))) float f32x16;

__device__ __forceinline__ float bf2f(unsigned short u) {
    union { unsigned int i; float f; } c; c.i = ((unsigned int)u) << 16; return c.f;
}
__device__ __forceinline__ unsigned short f2bf(float f) {
    union { float f; unsigned int i; } c; c.f = f;
    return (unsigned short)((c.i + 0x7FFFu + ((c.i >> 16) & 1u)) >> 16);
}

// ---------------------------------------------------------------------------
// Kernel 0: weights fp32 -> bf16 B-fragment layout, one tap per block.
//   wf[t][kg][co][j]: flat t*4096 + kg*512 + co*8 + j  (ci = kg*8+j)
// ---------------------------------------------------------------------------
__global__ void wprep_kernel(const float* __restrict__ w, unsigned short* __restrict__ wf)
{
    const int t = blockIdx.x;                 // tap 0..8
    for (int i = threadIdx.x; i < 4096; i += 256) {
        int kg = i >> 9;
        int r  = i & 511;
        int co = r >> 3;
        int j  = r & 7;
        int ci = kg * 8 + j;
        wf[t * 4096 + i] = f2bf(w[co * 576 + ci * 9 + t]);
    }
}

// ---------------------------------------------------------------------------
// Kernel 1: x NCHW fp32 -> xt NHWC bf16.  Tile: 32 px x 64 ci per block.
// ---------------------------------------------------------------------------
__global__ __launch_bounds__(256) void transpose_kernel(const float* __restrict__ x,
                                                        unsigned short* __restrict__ xt)
{
    __shared__ float t[64 * 36];          // [ci][pitch 36], quad-rotated
    const int tid = threadIdx.x;
    const int x0  = blockIdx.x * 32;
    const int y   = blockIdx.y;
    const int b   = blockIdx.z;

#pragma unroll
    for (int it = 0; it < 2; ++it) {
        int flat = it * 1024 + tid * 4;
        int px = flat & 31;
        int ci = flat >> 5;
        const float4 v = *(const float4*)(x + ((size_t)(b * 64 + ci) * HW + y * WW + x0 + px));
        int pxr = (px + 4 * (ci >> 3)) & 31;
        *(float4*)(t + ci * 36 + pxr) = v;
    }
    __syncthreads();

    int px = tid >> 3;
    int kg = tid & 7;
    short8 o;
#pragma unroll
    for (int j = 0; j < 8; ++j) {
        int ci = kg * 8 + j;
        float v = t[ci * 36 + ((px + 4 * (ci >> 3)) & 31)];
        o[j] = (short)f2bf(v);
    }
    *(short8*)(xt + ((size_t)(b * HW + y * WW + x0 + px) * 64 + kg * 8)) = o;
}

// ---------------------------------------------------------------------------
// Kernel 2: FUSED conv(3x3, MFMA implicit GEMM) + full epilogue.
//   Out tile 32x8 per block. x_conv recomputed on 34x10 halo tile:
//   340 px -> 11 M-tiles of 32 (waves take 3/3/3/2), N = 64 co = 2 tiles.
//   x staged 36x12 halo, bf16 NHWC granules, XOR-swizzled (55.3 KB).
//   B-fragments live in REGISTERS, loaded from global (L2-hot, 72 KB shared
//   device-wide) with a kg-outer loop -> the K-loop has ZERO barriers.
//   After taps, x_conv(+bias, zeroed outside image) is written back into the
//   SAME LDS buffer; epilogue (group stats over channels, depthwise diag
//   conv, affine, tanh*hardswish, residual, channel-LSE) runs in-block,
//   reading uniform params (diag w, bias, gn scale/bias) straight from
//   global via scalar loads.
//   LDS: xs 55296 B -> 2 blocks/CU; VGPR ~230 -> still 2 waves/SIMD.
// ---------------------------------------------------------------------------
__global__ __launch_bounds__(256, 2)
void conv_fused_kernel(const unsigned short* __restrict__ xt,
                       const unsigned short* __restrict__ wf,
                       const float* __restrict__ bias,
                       const float* __restrict__ w,
                       const float* __restrict__ gs,
                       const float* __restrict__ gb,
                       float* __restrict__ out)
{
    __shared__ unsigned short xs[432 * 64];        // x tile; reused for x_conv (340*64)

    const int tid = threadIdx.x;
    const int tx  = blockIdx.x * 32;
    const int ty  = blockIdx.y * 8;
    const int b   = blockIdx.z;
    const size_t bHW = (size_t)b * HW;

    // ---- stage x tile 36x12 (origin tx-2, ty-2), swizzled granules ----
#pragma unroll
    for (int it = 0; it < 14; ++it) {
        int g = tid + it * 256;
        if (g < 3456) {
            int pix = g >> 3;
            int kg  = g & 7;
            int hy  = (int)((unsigned)pix / 36u);
            int hx  = pix - hy * 36;
            int gy  = ty + hy - 2;
            int gx  = tx + hx - 2;
            short8 v = {};
            if ((unsigned)gy < (unsigned)HH && (unsigned)gx < (unsigned)WW)
                v = *(const short8*)(xt + ((bHW + gy * WW + gx) * 64 + kg * 8));
            *(short8*)(xs + (pix * 8 + (kg ^ (pix & 7))) * 8) = v;
        }
    }
    __syncthreads();

    const int lane = tid & 63;
    const int wv   = tid >> 6;
    const int m    = lane & 31;
    const int half = lane >> 5;
    const int nt   = (wv < 3) ? 3 : 2;   // M-tiles this wave owns
    const int t0   = wv * 3;

    // per-lane base pixel index in the 36-wide staging grid, per M-tile
    int pb[3];
#pragma unroll
    for (int i = 0; i < 3; ++i) {
        int p = (t0 + i) * 32 + m;
        if (p > 339) p = 339;            // clamp (results discarded at store)
        int py = (int)((unsigned)p / 34u);
        pb[i] = py * 36 + (p - py * 34);
    }

    f32x16 acc[3][2];
#pragma unroll
    for (int i = 0; i < 3; ++i)
#pragma unroll
        for (int n = 0; n < 2; ++n)
#pragma unroll
            for (int r = 0; r < 16; ++r) acc[i][n][r] = 0.f;

    // ---- K-loop: kg-outer, B-frags in registers, no barriers ----
#pragma unroll 1
    for (int ks = 0; ks < 4; ++ks) {
        const int kg = ks * 2 + half;
        const unsigned short* wfk = wf + kg * 512 + m * 8;
        short8 bfr[9][2];
#pragma unroll
        for (int t9 = 0; t9 < 9; ++t9) {
            bfr[t9][0] = *(const short8*)(wfk + t9 * 4096);
            bfr[t9][1] = *(const short8*)(wfk + t9 * 4096 + 256);
        }
#pragma unroll
        for (int t9 = 0; t9 < 9; ++t9) {
            const int off = (t9 / 3) * 36 + (t9 - 3 * (t9 / 3));
#pragma unroll
            for (int i = 0; i < 3; ++i) {
                if (i < nt) {
                    int pi = pb[i] + off;
                    short8 a = *(const short8*)(xs + (pi * 8 + (kg ^ (pi & 7))) * 8);
                    acc[i][0] = __builtin_amdgcn_mfma_f32_32x32x16_bf16(a, bfr[t9][0], acc[i][0], 0, 0, 0);
                    acc[i][1] = __builtin_amdgcn_mfma_f32_32x32x16_bf16(a, bfr[t9][1], acc[i][1], 0, 0, 0);
                }
            }
        }
    }
    __syncthreads();   // all a-reads done before xs is overwritten

    // ---- write x_conv (+bias; zero outside image) into xs (34x10 grid) ----
    const float bv0 = bias[m];
    const float bv1 = bias[32 + m];
    const int kg0 = m >> 3;
    const int kg1 = 4 + (m >> 3);
#pragma unroll
    for (int i = 0; i < 3; ++i) {
        if (i < nt) {
            const int p0  = (t0 + i) * 32;              // wave-uniform
            const int pyA = (int)((unsigned)p0 / 34u);  // scalar div
            const int bnd = pyA * 34 + 34;
            const int pxA = p0 - pyA * 34;
#pragma unroll
            for (int reg = 0; reg < 16; ++reg) {
                int row = (reg & 3) + 8 * (reg >> 2) + 4 * half;
                int p   = p0 + row;
                bool hi = p >= bnd;
                int py  = pyA + (hi ? 1 : 0);
                int px  = pxA + row - (hi ? 34 : 0);
                int gy  = ty + py - 1;
                int gx  = tx + px - 1;
                bool inr = (p < 340) & ((unsigned)gy < (unsigned)HH) &
                           ((unsigned)gx < (unsigned)WW);
                if (p < 340) {
                    unsigned short v0 = inr ? f2bf(acc[i][0][reg] + bv0) : (unsigned short)0;
                    unsigned short v1 = inr ? f2bf(acc[i][1][reg] + bv1) : (unsigned short)0;
                    xs[(p * 8 + (kg0 ^ (p & 7))) * 8 + (m & 7)] = v0;
                    xs[(p * 8 + (kg1 ^ (p & 7))) * 8 + (m & 7)] = v1;
                }
            }
        }
    }
    __syncthreads();

    // ---- epilogue: one thread per output pixel (32x8) ----
    const int lx = tid & 31;
    const int ly = tid >> 5;

    float mmax = -INFINITY, ssum = 0.f;

#pragma unroll 2
    for (int kg = 0; kg < 8; ++kg) {     // granule == groupnorm group (8 ch)
        short8 n9[9];
#pragma unroll
        for (int dy = 0; dy < 3; ++dy)
#pragma unroll
            for (int dx = 0; dx < 3; ++dx) {
                int pl = (ly + dy) * 34 + (lx + dx);
                n9[dy * 3 + dx] = *(const short8*)(xs + (pl * 8 + (kg ^ (pl & 7))) * 8);
            }
        float xcv[8], s = 0.f, s2 = 0.f;
#pragma unroll
        for (int c = 0; c < 8; ++c) {
            xcv[c] = bf2f((unsigned short)n9[4][c]);
            s += xcv[c];
            s2 = fmaf(xcv[c], xcv[c], s2);
        }
        float mean = s * 0.125f;
        float var  = fmaxf(s2 * 0.125f - mean * mean, 0.f);
        float inv  = rsqrtf(var + EPS);

#pragma unroll
        for (int c = 0; c < 8; ++c) {
            int ch = kg * 8 + c;
            float a = bias[ch];                       // uniform -> s_load
#pragma unroll
            for (int k = 0; k < 9; ++k)
                a = fmaf(w[ch * 585 + k], bf2f((unsigned short)n9[k][c]), a);
            float nrm  = (a - mean) * inv * gs[ch] + gb[ch];
            float gate = fminf(fmaxf((nrm + 3.f) * (1.f / 6.f), 0.f), 1.f);
            float e    = __expf(2.f * nrm);
            float th   = 1.f - 2.f / (e + 1.f);
            float v    = xcv[c] + th * gate;
            float nm   = fmaxf(mmax, v);
            ssum = fmaf(ssum, __expf(mmax - nm), __expf(v - nm));
            mmax = nm;
        }
    }

    out[bHW + (ty + ly) * WW + tx + lx] = mmax + __logf(ssum);
}

// ---------------------------------------------------------------------------
extern "C" void kernel_launch(void* const* d_in, const int* in_sizes, int n_in,
                              void* d_out, int out_size, void* d_ws, size_t ws_size,
                              hipStream_t stream)
{
    (void)in_sizes; (void)n_in; (void)out_size;
    const float* x   = (const float*)d_in[0];
    const float* w   = (const float*)d_in[1];
    const float* cbp = (const float*)d_in[2];
    const float* gsp = (const float*)d_in[3];
    const float* gbp = (const float*)d_in[4];
    float* out = (float*)d_out;

    const size_t XB = (size_t)134217728;   // NHWC bf16 x tensor (128 MiB)
    unsigned short* xtp = (unsigned short*)d_ws;
    unsigned short* wfp = (ws_size >= XB + 73728)
                              ? (unsigned short*)((char*)d_ws + XB)
                              : (unsigned short*)d_out;

    wprep_kernel<<<dim3(9), dim3(256), 0, stream>>>(w, wfp);
    transpose_kernel<<<dim3(8, 256, 16), dim3(256), 0, stream>>>(x, xtp);
    conv_fused_kernel<<<dim3(8, 32, 16), dim3(256), 0, stream>>>(xtp, wfp, cbp, w, gsp, gbp, out);
}